// Round 2
// baseline (429.021 us; speedup 1.0000x reference)
//
#include <hip/hip_runtime.h>
#include <cstdint>
#include <cstddef>

typedef __attribute__((ext_vector_type(8))) short bf16x8;
typedef __attribute__((ext_vector_type(4))) float f32x4;
typedef __attribute__((ext_vector_type(8))) unsigned short ushort8;

#define FIX_CAP 65536
#define MARGIN 1e-3f   // exact-float gap test (proven criterion)

__device__ __forceinline__ unsigned short f2bf(float f) {
  union { float f; unsigned int u; } x; x.f = f;
  unsigned int r = (x.u + 0x7fffu + ((x.u >> 16) & 1u)) >> 16;  // RNE
  return (unsigned short)r;
}
__device__ __forceinline__ float bf2f(unsigned short h) {
  union { unsigned int u; float f; } x; x.u = ((unsigned int)h) << 16;
  return x.f;
}
// monotone float -> sortable u32 ordinal (exact, bijective)
__device__ __forceinline__ unsigned int f2ord(float v) {
  unsigned int s = __float_as_uint(v);
  return s ^ ((unsigned int)((int)s >> 31) | 0x80000000u);
}
__device__ __forceinline__ float ord2f(unsigned int o) {
  unsigned int s = (o & 0x80000000u) ? (o ^ 0x80000000u) : ~o;
  return __uint_as_float(s);
}

// ---------------------------------------------------------------------------
// kprep: fused {zero Mt + cnt, W3->bf16, W1->hi/lo bf16, const[k]=W3[k,:]·b2+b3[k]}
// ---------------------------------------------------------------------------
__global__ __launch_bounds__(256) void kprep(
    float* __restrict__ Mt, int* __restrict__ cnt,
    const float* __restrict__ W3, unsigned short* __restrict__ W3b,
    const float* __restrict__ W1, unsigned short* __restrict__ w1h,
    unsigned short* __restrict__ w1l,
    const float* __restrict__ b2, const float* __restrict__ b3,
    float* __restrict__ constv) {
  __shared__ float red[4];
  const int bid = blockIdx.x;
  const int t = threadIdx.x;
  if (bid < 512) {
    int e = bid * 256 + t;  // 2 MB of zeros
    ((float4*)Mt)[e] = (float4){0.f, 0.f, 0.f, 0.f};
    if (e == 0) cnt[0] = 0;
  } else if (bid < 768) {
    int e = ((bid - 512) * 256 + t) * 8;  // W3 -> bf16
    float4 f0 = *(const float4*)(W3 + e);
    float4 f1 = *(const float4*)(W3 + e + 4);
    ushort8 v;
    v[0] = f2bf(f0.x); v[1] = f2bf(f0.y); v[2] = f2bf(f0.z); v[3] = f2bf(f0.w);
    v[4] = f2bf(f1.x); v[5] = f2bf(f1.y); v[6] = f2bf(f1.z); v[7] = f2bf(f1.w);
    *(ushort8*)(W3b + e) = v;
  } else if (bid < 1024) {
    int e = ((bid - 768) * 256 + t) * 8;  // W1 -> hi/lo bf16
    float ff[8];
    *(float4*)&ff[0] = *(const float4*)(W1 + e);
    *(float4*)&ff[4] = *(const float4*)(W1 + e + 4);
    ushort8 h, l;
#pragma unroll
    for (int i = 0; i < 8; i++) {
      unsigned short hi = f2bf(ff[i]);
      h[i] = hi;
      l[i] = f2bf(ff[i] - bf2f(hi));
    }
    *(ushort8*)(w1h + e) = h;
    *(ushort8*)(w1l + e) = l;
  } else {
    int k = bid - 1024;  // const[k]
    float s = 0.f;
    for (int j = t; j < 4096; j += 256) s += W3[k * 4096 + j] * b2[j];
#pragma unroll
    for (int mk = 1; mk < 64; mk <<= 1) s += __shfl_xor(s, mk, 64);
    if ((t & 63) == 0) red[t >> 6] = s;
    __syncthreads();
    if (t == 0) constv[k] = red[0] + red[1] + red[2] + red[3] + b3[k];
  }
}

// ---------------------------------------------------------------------------
// K1 v2: occupancy-first redesign.
//   grid 1024 blocks x 32 rows (was 512 x 64) -> LDS 34.4 KB, VGPR<=128,
//   __launch_bounds__(256,4): 4 blocks/CU = 16 waves/CU = 4 waves/SIMD
//   (round-1 counters: Occupancy 23%, MfmaUtil 24%, VALUBusy 25% ->
//   latency-bound at 2 waves/SIMD; this doubles latency hiding).
// Epilogue v2 (2 barriers/seg, no phase-C recompute):
//   phase A: per (mt,reg) slot, exact sorted ordinal pair (top-2 of 4 nt)
//            -> kbuf[row][entry] (b64 writes, conflict-free layout 132-stride)
//   phase B: 8 threads/row merge 8 pairs each (exact top-2 of row) +
//            3-step shfl merge; leader emits near-tie flag (EXACT float gap,
//            proven 1e-3 margin) and winner ordinal to rowres.
//   phase C: "claim" — the lane whose kept ordinal equals the winner stores
//            the col index. Unique unless an exact tie, and exact ties have
//            gap 0 < margin -> always flagged -> k1_fix overwrites
//            deterministically. So no tie-break logic needed in fast path.
// MFMA 3-term split order identical to proven kernel -> bit-identical logits.
// ---------------------------------------------------------------------------
__global__ __launch_bounds__(256, 4) void k1_mfma(
    const float* __restrict__ x, const unsigned short* __restrict__ w1h,
    const unsigned short* __restrict__ w1l, const float* __restrict__ b1,
    int* __restrict__ idxbuf, int* __restrict__ cnt, int* __restrict__ list) {
  __shared__ unsigned short xsh[32 * 136];  // stride 136 shorts
  __shared__ unsigned short xsl[32 * 136];
  __shared__ unsigned int kbuf[32 * 132];   // [row][64 pairs], stride 132 dwords
  __shared__ unsigned int rowres[32];       // winner ordinal per row

  const int t = threadIdx.x;
  const int r0 = blockIdx.x * 32;

  // ---- stage x rows 32x128, hi/lo bf16 split (once per block) ----
#pragma unroll
  for (int it = 0; it < 2; it++) {
    int ch = it * 256 + t;          // 512 chunks of 8 elems
    int row = ch >> 4, k8 = ch & 15;
    float ff[8];
    *(float4*)&ff[0] = *(const float4*)(x + (r0 + row) * 128 + k8 * 8);
    *(float4*)&ff[4] = *(const float4*)(x + (r0 + row) * 128 + k8 * 8 + 4);
    ushort8 h, l;
#pragma unroll
    for (int i = 0; i < 8; i++) {
      unsigned short hi = f2bf(ff[i]);
      h[i] = hi;
      l[i] = f2bf(ff[i] - bf2f(hi));
    }
    *(ushort8*)&xsh[row * 136 + k8 * 8] = h;
    *(ushort8*)&xsl[row * 136 + k8 * 8] = l;
  }
  __syncthreads();

  const int lane = t & 63, wv = t >> 6;
  const int m = lane & 15, q = lane >> 4;
  const int rowB = t >> 3, partB = t & 7;  // phase-B: 8 threads per row

  // loop-invariant B pointers: advance by one seg (256 cols * 128) each iter
  const unsigned short* bhp = w1h + (size_t)(wv * 64 + m) * 128 + q * 8;
  const unsigned short* blp = w1l + (size_t)(wv * 64 + m) * 128 + q * 8;
  const float* b1p = b1 + wv * 64 + m;

  for (int seg = 0; seg < 16; ++seg) {
    f32x4 acc[2][4];
#pragma unroll
    for (int mt = 0; mt < 2; mt++)
#pragma unroll
      for (int nt = 0; nt < 4; nt++) acc[mt][nt] = (f32x4){0.f, 0.f, 0.f, 0.f};

#pragma unroll
    for (int ks = 0; ks < 4; ks++) {
      const int k0 = ks * 32;
      bf16x8 ah[2], al[2];
#pragma unroll
      for (int mt = 0; mt < 2; mt++) {
        ah[mt] = *(const bf16x8*)&xsh[(mt * 16 + m) * 136 + k0 + q * 8];
        al[mt] = *(const bf16x8*)&xsl[(mt * 16 + m) * 136 + k0 + q * 8];
      }
#pragma unroll
      for (int nt = 0; nt < 4; nt++) {
        bf16x8 bh = *(const bf16x8*)(bhp + nt * 2048 + k0);
        bf16x8 bl = *(const bf16x8*)(blp + nt * 2048 + k0);
#pragma unroll
        for (int mt = 0; mt < 2; mt++) {
          acc[mt][nt] = __builtin_amdgcn_mfma_f32_16x16x32_bf16(ah[mt], bh, acc[mt][nt], 0, 0, 0);
          acc[mt][nt] = __builtin_amdgcn_mfma_f32_16x16x32_bf16(ah[mt], bl, acc[mt][nt], 0, 0, 0);
          acc[mt][nt] = __builtin_amdgcn_mfma_f32_16x16x32_bf16(al[mt], bh, acc[mt][nt], 0, 0, 0);
        }
      }
    }

    // ---- phase A: exact ordinals; per-slot sorted top-2 pair -> kbuf ----
    float bias[4];
#pragma unroll
    for (int nt = 0; nt < 4; nt++) bias[nt] = b1p[nt * 16];

    unsigned int o[2][4][4];  // [mt][reg][nt] kept for phase-C claim
#pragma unroll
    for (int mt = 0; mt < 2; mt++)
#pragma unroll
      for (int reg = 0; reg < 4; reg++) {
#pragma unroll
        for (int nt = 0; nt < 4; nt++)
          o[mt][reg][nt] = f2ord(acc[mt][nt][reg] + bias[nt]);
        unsigned int o0 = o[mt][reg][0], o1 = o[mt][reg][1];
        unsigned int o2 = o[mt][reg][2], o3 = o[mt][reg][3];
        unsigned int K1 = o0 > o1 ? o0 : o1;
        unsigned int K2 = o0 > o1 ? o1 : o0;
        unsigned int mx = K1 > o2 ? K1 : o2;
        unsigned int mn = K1 > o2 ? o2 : K1;
        K1 = mx; K2 = K2 > mn ? K2 : mn;
        mx = K1 > o3 ? K1 : o3;
        mn = K1 > o3 ? o3 : K1;
        K1 = mx; K2 = K2 > mn ? K2 : mn;
        int row = mt * 16 + q * 4 + reg;
        uint2 pr; pr.x = K1; pr.y = K2;
        *(uint2*)&kbuf[row * 132 + (wv * 16 + m) * 2] = pr;
      }
    __syncthreads();

    // ---- phase B: exact row top-2 via sorted-pair merges ----
    unsigned int K1 = 0u, K2 = 0u;
    {
      const uint4* kp = (const uint4*)&kbuf[rowB * 132 + partB * 16];
#pragma unroll
      for (int i = 0; i < 4; i++) {
        uint4 u = kp[i];
        // merge pair (u.x,u.y)
        unsigned int mn = K1 < u.x ? K1 : u.x;
        unsigned int mx = K1 < u.x ? u.x : K1;
        unsigned int sel = K1 >= u.x ? K2 : u.y;
        unsigned int c = sel > mn ? sel : mn;
        K1 = mx; K2 = K2 > c ? K2 : c;
        // merge pair (u.z,u.w)
        mn = K1 < u.z ? K1 : u.z;
        mx = K1 < u.z ? u.z : K1;
        sel = K1 >= u.z ? K2 : u.w;
        c = sel > mn ? sel : mn;
        K1 = mx; K2 = K2 > c ? K2 : c;
      }
#pragma unroll
      for (int msk = 1; msk <= 4; msk <<= 1) {
        unsigned int p1 = (unsigned int)__shfl_xor((int)K1, msk, 64);
        unsigned int p2 = (unsigned int)__shfl_xor((int)K2, msk, 64);
        unsigned int mn = K1 < p1 ? K1 : p1;
        unsigned int mx = K1 < p1 ? p1 : K1;
        unsigned int sel = K1 >= p1 ? K2 : p2;
        unsigned int c = sel > mn ? sel : mn;
        K1 = mx; K2 = K2 > c ? K2 : c;
      }
      if (partB == 0) {
        rowres[rowB] = K1;
        float v1 = ord2f(K1), v2 = ord2f(K2);
        if (v1 - v2 < MARGIN) {
          int p = atomicAdd(cnt, 1);
          if (p < FIX_CAP) list[p] = ((r0 + rowB) << 4) | seg;
        }
      }
    }
    __syncthreads();

    // ---- phase C: claim-write the winner index (unique unless flagged) ----
#pragma unroll
    for (int mt = 0; mt < 2; mt++)
#pragma unroll
      for (int reg = 0; reg < 4; reg++) {
        int row = mt * 16 + q * 4 + reg;
        unsigned int win = rowres[row];
        int colsel = -1;
#pragma unroll
        for (int nt = 3; nt >= 0; nt--)
          if (o[mt][reg][nt] == win) colsel = nt;
        if (colsel >= 0)
          idxbuf[(r0 + row) * 16 + seg] = wv * 64 + colsel * 16 + m;
      }

    bhp += 32768; blp += 32768; b1p += 256;
    // kbuf next written in phase A after this point: last read was phase B
    // (before the barrier above) -> safe with 2 barriers/seg.
  }
}

// ---------------------------------------------------------------------------
// K1fix: exact fp32 recompute for flagged (b,seg) — unchanged proven numerics.
// ---------------------------------------------------------------------------
__global__ __launch_bounds__(256) void k1_fix(
    const float* __restrict__ x, const float* __restrict__ W1,
    const float* __restrict__ b1, const int* __restrict__ cnt,
    const int* __restrict__ list, int* __restrict__ idxbuf) {
  __shared__ float redv[4];
  __shared__ int   redi[4];
  const int t = threadIdx.x;
  const int lane = t & 63, wv = t >> 6;
  int n = cnt[0]; if (n > FIX_CAP) n = FIX_CAP;
  for (int e = blockIdx.x; e < n; e += gridDim.x) {
    int pk = list[e];
    int b = pk >> 4, seg = pk & 15;
    int c = seg * 256 + t;
    float a = b1[c];
    const float4* xr = (const float4*)(x + b * 128);
    const float4* wr = (const float4*)(W1 + (size_t)c * 128);
#pragma unroll 8
    for (int k4 = 0; k4 < 32; k4++) {
      float4 xv = xr[k4];
      float4 wv4 = wr[k4];
      a = fmaf(xv.x, wv4.x, a);
      a = fmaf(xv.y, wv4.y, a);
      a = fmaf(xv.z, wv4.z, a);
      a = fmaf(xv.w, wv4.w, a);
    }
    float v = a; int li = t;
#pragma unroll
    for (int msk = 1; msk < 64; msk <<= 1) {
      float u = __shfl_xor(v, msk, 64);
      int ju = __shfl_xor(li, msk, 64);
      if (u > v || (u == v && ju < li)) { v = u; li = ju; }
    }
    if (lane == 0) { redv[wv] = v; redi[wv] = li; }
    __syncthreads();
    if (t == 0) {
      float bv = redv[0]; int bi = redi[0];
#pragma unroll
      for (int w = 1; w < 4; w++) {
        if (redv[w] > bv || (redv[w] == bv && redi[w] < bi)) { bv = redv[w]; bi = redi[w]; }
      }
      idxbuf[b * 16 + seg] = bi;
    }
    __syncthreads();
  }
}

// ---------------------------------------------------------------------------
// K2: Mt[c,k] += sum_j W2[j,c]*W3[k,j] via bf16 MFMA, split-K=8 (unchanged).
// ---------------------------------------------------------------------------
__global__ __launch_bounds__(256) void k2_mfma(const float* __restrict__ W2,
                                               const unsigned short* __restrict__ W3b,
                                               float* __restrict__ Mt) {
  const int t = threadIdx.x;
  const int lane = t & 63, wv = t >> 6;
  const int c0 = (blockIdx.x * 4 + wv) * 16;
  const int jq = blockIdx.y;
  const int m = lane & 15, q = lane >> 4;
  f32x4 acc[8];
#pragma unroll
  for (int nt = 0; nt < 8; nt++) acc[nt] = (f32x4){0.f, 0.f, 0.f, 0.f};

  for (int it = 0; it < 16; it++) {
    const int j0 = jq * 512 + it * 32;
    union { bf16x8 v; unsigned short u[8]; } a;
    const float* ap = W2 + (size_t)(j0 + q * 8) * 4096 + c0 + m;
#pragma unroll
    for (int i = 0; i < 8; i++) a.u[i] = f2bf(ap[(size_t)i * 4096]);
#pragma unroll
    for (int nt = 0; nt < 8; nt++) {
      bf16x8 b = *(const bf16x8*)(W3b + (nt * 16 + m) * 4096 + j0 + q * 8);
      acc[nt] = __builtin_amdgcn_mfma_f32_16x16x32_bf16(a.v, b, acc[nt], 0, 0, 0);
    }
  }
#pragma unroll
  for (int nt = 0; nt < 8; nt++)
#pragma unroll
    for (int r = 0; r < 4; r++)
      atomicAdd(&Mt[(size_t)(c0 + q * 4 + r) * 128 + nt * 16 + m], acc[nt][r]);
}

// ---------------------------------------------------------------------------
// K3: out[b,k] = const[k] + sum_g Mt[g*256 + idx[b,g], k]  (unchanged)
// ---------------------------------------------------------------------------
__global__ __launch_bounds__(256) void k3_gather(const int* __restrict__ idxbuf,
                                                 const float* __restrict__ Mt,
                                                 const float* __restrict__ constv,
                                                 float* __restrict__ out) {
  const int t = threadIdx.x;
  const int w = t >> 6;
  const int lane = t & 63;
  const int b = blockIdx.x * 4 + w;
  float a0 = constv[lane];
  float a1 = constv[lane + 64];
  const int* ib = idxbuf + b * 16;
  int cg[16];
#pragma unroll
  for (int g = 0; g < 16; g++) cg[g] = g * 256 + ib[g];
#pragma unroll
  for (int g = 0; g < 16; g++) {
    const float* mrow = Mt + (size_t)cg[g] * 128;
    a0 += mrow[lane];
    a1 += mrow[lane + 64];
  }
  out[b * 128 + lane] = a0;
  out[b * 128 + lane + 64] = a1;
}

// ---------------------------------------------------------------------------
extern "C" void kernel_launch(void* const* d_in, const int* in_sizes, int n_in,
                              void* d_out, int out_size, void* d_ws, size_t ws_size,
                              hipStream_t stream) {
  const float* x  = (const float*)d_in[0];
  const float* W1 = (const float*)d_in[1];
  const float* b1 = (const float*)d_in[2];
  const float* W2 = (const float*)d_in[3];
  const float* b2 = (const float*)d_in[4];
  const float* W3 = (const float*)d_in[5];
  const float* b3 = (const float*)d_in[6];
  float* out = (float*)d_out;

  char* w = (char*)d_ws;
  int* idxbuf         = (int*)(w);                           // 2 MB
  unsigned short* W3b = (unsigned short*)(w + (2u << 20));   // 1 MB
  float* Mt           = (float*)(w + (3u << 20));            // 2 MB
  unsigned short* w1h = (unsigned short*)(w + (5u << 20));   // 1 MB
  unsigned short* w1l = (unsigned short*)(w + (6u << 20));   // 1 MB
  float* constv       = (float*)(w + (7u << 20));            // 512 B
  int* cnt            = (int*)(w + (7u << 20) + 1024);       // 4 B
  int* fixlist        = (int*)(w + (7u << 20) + 4096);       // 256 KB

  kprep<<<1152, 256, 0, stream>>>(Mt, cnt, W3, W3b, W1, w1h, w1l, b2, b3, constv);
  k1_mfma<<<1024, 256, 0, stream>>>(x, w1h, w1l, b1, idxbuf, cnt, fixlist);
  k1_fix<<<1024, 256, 0, stream>>>(x, W1, b1, cnt, fixlist, idxbuf);
  k2_mfma<<<dim3(64, 8), 256, 0, stream>>>(W2, W3b, Mt);
  k3_gather<<<8192, 256, 0, stream>>>(idxbuf, Mt, constv, out);
}

// Round 3
// 419.623 us; speedup vs baseline: 1.0224x; 1.0224x over previous
//
#include <hip/hip_runtime.h>
#include <cstdint>
#include <cstddef>

typedef __attribute__((ext_vector_type(8))) short bf16x8;
typedef __attribute__((ext_vector_type(4))) float f32x4;
typedef __attribute__((ext_vector_type(8))) unsigned short ushort8;

#define FIX_CAP 65536
// quantized-key flag margin: proven 1e-3 + 2*2.4e-4 key-truncation slack (round-1 verified)
#define MARGIN2 1.5e-3f

__device__ __forceinline__ unsigned short f2bf(float f) {
  union { float f; unsigned int u; } x; x.f = f;
  unsigned int r = (x.u + 0x7fffu + ((x.u >> 16) & 1u)) >> 16;  // RNE
  return (unsigned short)r;
}
__device__ __forceinline__ float bf2f(unsigned short h) {
  union { unsigned int u; float f; } x; x.u = ((unsigned int)h) << 16;
  return x.f;
}
// monotone float -> sortable u32 ordinal
__device__ __forceinline__ unsigned int f2ord(float v) {
  unsigned int s = __float_as_uint(v);
  return s ^ ((unsigned int)((int)s >> 31) | 0x80000000u);
}
__device__ __forceinline__ float ord2f(unsigned int o) {
  unsigned int s = (o & 0x80000000u) ? (o ^ 0x80000000u) : ~o;
  return __uint_as_float(s);
}

// ---------------------------------------------------------------------------
// kprep: fused {zero Mt + cnt, W3->bf16, W1->hi/lo bf16, const[k]=W3[k,:]·b2+b3[k]}
// ---------------------------------------------------------------------------
__global__ __launch_bounds__(256) void kprep(
    float* __restrict__ Mt, int* __restrict__ cnt,
    const float* __restrict__ W3, unsigned short* __restrict__ W3b,
    const float* __restrict__ W1, unsigned short* __restrict__ w1h,
    unsigned short* __restrict__ w1l,
    const float* __restrict__ b2, const float* __restrict__ b3,
    float* __restrict__ constv) {
  __shared__ float red[4];
  const int bid = blockIdx.x;
  const int t = threadIdx.x;
  if (bid < 512) {
    int e = bid * 256 + t;  // 2 MB of zeros
    ((float4*)Mt)[e] = (float4){0.f, 0.f, 0.f, 0.f};
    if (e == 0) cnt[0] = 0;
  } else if (bid < 768) {
    int e = ((bid - 512) * 256 + t) * 8;  // W3 -> bf16
    float4 f0 = *(const float4*)(W3 + e);
    float4 f1 = *(const float4*)(W3 + e + 4);
    ushort8 v;
    v[0] = f2bf(f0.x); v[1] = f2bf(f0.y); v[2] = f2bf(f0.z); v[3] = f2bf(f0.w);
    v[4] = f2bf(f1.x); v[5] = f2bf(f1.y); v[6] = f2bf(f1.z); v[7] = f2bf(f1.w);
    *(ushort8*)(W3b + e) = v;
  } else if (bid < 1024) {
    int e = ((bid - 768) * 256 + t) * 8;  // W1 -> hi/lo bf16
    float ff[8];
    *(float4*)&ff[0] = *(const float4*)(W1 + e);
    *(float4*)&ff[4] = *(const float4*)(W1 + e + 4);
    ushort8 h, l;
#pragma unroll
    for (int i = 0; i < 8; i++) {
      unsigned short hi = f2bf(ff[i]);
      h[i] = hi;
      l[i] = f2bf(ff[i] - bf2f(hi));
    }
    *(ushort8*)(w1h + e) = h;
    *(ushort8*)(w1l + e) = l;
  } else {
    int k = bid - 1024;  // const[k]
    float s = 0.f;
    for (int j = t; j < 4096; j += 256) s += W3[k * 4096 + j] * b2[j];
#pragma unroll
    for (int mk = 1; mk < 64; mk <<= 1) s += __shfl_xor(s, mk, 64);
    if ((t & 63) == 0) red[t >> 6] = s;
    __syncthreads();
    if (t == 0) constv[k] = red[0] + red[1] + red[2] + red[3] + b3[k];
  }
}

// ---------------------------------------------------------------------------
// K1 v3: round-1 structure (64 rows, mt=4: 4 independent MFMA chains, best
// measured per-wave MFMA density) + seg-split grid for occupancy:
//   grid (512 row-blocks, 2 seg-groups of 8 segs) = 1024 blocks.
//   LDS 52.7 KB -> 3 blocks/CU resident = 12 waves/CU = 3 waves/SIMD
//   (round 1 was grid-limited to 2 waves/SIMD at 512 blocks; round 2 showed
//   occupancy without mt=4 ILP is a net loss -> combine both).
// Epilogue: round-1 verbatim (harness-passed): col-packed quantized keys,
// phase A top-of-4 -> kbuf, phase B 4 threads/row scan + 2-step shfl top-2,
// phase C winner-internal-2nd, margin 1.5e-3 superset flag criterion.
// MFMA 3-term split order identical -> bit-identical logits.
// ---------------------------------------------------------------------------
__global__ __launch_bounds__(256, 3) void k1_mfma(
    const float* __restrict__ x, const unsigned short* __restrict__ w1h,
    const unsigned short* __restrict__ w1l, const float* __restrict__ b1,
    int* __restrict__ idxbuf, int* __restrict__ cnt, int* __restrict__ list) {
  __shared__ unsigned short xsh[64 * 136];  // stride 136 shorts
  __shared__ unsigned short xsl[64 * 136];
  __shared__ unsigned int kbuf[64 * 68];    // [row][entry(wv*16+m)], stride 68
  __shared__ unsigned int rowres[64];       // winner key per row
  __shared__ unsigned int rowres2[64];      // winner-entry internal 2nd key per row

  const int t = threadIdx.x;
  const int r0 = blockIdx.x * 64;
  const int sg0 = blockIdx.y * 8;  // this block's 8 segments

  // ---- stage x rows 64x128, on-the-fly hi/lo bf16 split (once per block) ----
#pragma unroll
  for (int it = 0; it < 4; it++) {
    int ch = it * 256 + t;          // 1024 chunks of 8 elems
    int row = ch >> 4, k8 = ch & 15;
    float ff[8];
    *(float4*)&ff[0] = *(const float4*)(x + (r0 + row) * 128 + k8 * 8);
    *(float4*)&ff[4] = *(const float4*)(x + (r0 + row) * 128 + k8 * 8 + 4);
    ushort8 h, l;
#pragma unroll
    for (int i = 0; i < 8; i++) {
      unsigned short hi = f2bf(ff[i]);
      h[i] = hi;
      l[i] = f2bf(ff[i] - bf2f(hi));
    }
    *(ushort8*)&xsh[row * 136 + k8 * 8] = h;
    *(ushort8*)&xsl[row * 136 + k8 * 8] = l;
  }
  __syncthreads();

  const int lane = t & 63, wv = t >> 6;
  const int m = lane & 15, q = lane >> 4;
  const int browB = t >> 2, partB = t & 3;  // phase-B mapping: 4 threads per row

  for (int s = 0; s < 8; ++s) {
    const int seg = sg0 + s;
    const int cbase = seg * 256 + wv * 64;  // global col of (nt=0, n16=0)

    f32x4 acc[4][4];
#pragma unroll
    for (int mt = 0; mt < 4; mt++)
#pragma unroll
      for (int nt = 0; nt < 4; nt++) acc[mt][nt] = (f32x4){0.f, 0.f, 0.f, 0.f};

#pragma unroll
    for (int ks = 0; ks < 4; ks++) {
      const int k0 = ks * 32;
      bf16x8 ah[4], al[4];
#pragma unroll
      for (int mt = 0; mt < 4; mt++) {
        ah[mt] = *(const bf16x8*)&xsh[(mt * 16 + m) * 136 + k0 + q * 8];
        al[mt] = *(const bf16x8*)&xsl[(mt * 16 + m) * 136 + k0 + q * 8];
      }
#pragma unroll
      for (int nt = 0; nt < 4; nt++) {
        const size_t woff = (size_t)(cbase + nt * 16 + m) * 128 + k0 + q * 8;
        bf16x8 bh = *(const bf16x8*)(w1h + woff);
        bf16x8 bl = *(const bf16x8*)(w1l + woff);
#pragma unroll
        for (int mt = 0; mt < 4; mt++) {
          acc[mt][nt] = __builtin_amdgcn_mfma_f32_16x16x32_bf16(ah[mt], bh, acc[mt][nt], 0, 0, 0);
          acc[mt][nt] = __builtin_amdgcn_mfma_f32_16x16x32_bf16(ah[mt], bl, acc[mt][nt], 0, 0, 0);
          acc[mt][nt] = __builtin_amdgcn_mfma_f32_16x16x32_bf16(al[mt], bh, acc[mt][nt], 0, 0, 0);
        }
      }
    }

    // ---- phase A: per-thread max-key over its 4 cols per row-slot ----
    float bias[4];
#pragma unroll
    for (int nt = 0; nt < 4; nt++) bias[nt] = b1[cbase + nt * 16 + m];

#pragma unroll
    for (int mt = 0; mt < 4; mt++)
#pragma unroll
      for (int reg = 0; reg < 4; reg++) {
        unsigned int kk = 0u;
#pragma unroll
        for (int nt = 0; nt < 4; nt++) {
          float v = acc[mt][nt][reg] + bias[nt];
          unsigned int col = (unsigned)(wv * 64 + nt * 16 + m);
          unsigned int key = (f2ord(v) & 0xFFFFFF00u) | (255u - col);
          kk = kk > key ? kk : key;
        }
        kbuf[(mt * 16 + q * 4 + reg) * 68 + wv * 16 + m] = kk;
      }
    __syncthreads();

    // ---- phase B: 4 threads per row scan 16 entries each, top-2 of entry-tops ----
    unsigned int K1 = 0u, K2 = 0u;
    {
      const uint4* kp = (const uint4*)&kbuf[browB * 68 + partB * 16];
#pragma unroll
      for (int i = 0; i < 4; i++) {
        uint4 u = kp[i];
        unsigned int kv0 = u.x, kv1 = u.y, kv2 = u.z, kv3 = u.w;
        unsigned int hi, lo;
        hi = K1 > kv0 ? K1 : kv0; lo = K1 > kv0 ? kv0 : K1; K1 = hi; K2 = K2 > lo ? K2 : lo;
        hi = K1 > kv1 ? K1 : kv1; lo = K1 > kv1 ? kv1 : K1; K1 = hi; K2 = K2 > lo ? K2 : lo;
        hi = K1 > kv2 ? K1 : kv2; lo = K1 > kv2 ? kv2 : K1; K1 = hi; K2 = K2 > lo ? K2 : lo;
        hi = K1 > kv3 ? K1 : kv3; lo = K1 > kv3 ? kv3 : K1; K1 = hi; K2 = K2 > lo ? K2 : lo;
      }
#pragma unroll
      for (int msk = 1; msk <= 2; msk <<= 1) {
        unsigned int o1 = (unsigned int)__shfl_xor((int)K1, msk, 64);
        unsigned int o2 = (unsigned int)__shfl_xor((int)K2, msk, 64);
        unsigned int hi = K1 > o1 ? K1 : o1;
        unsigned int lo = K1 > o1 ? o1 : K1;
        unsigned int m2 = K2 > o2 ? K2 : o2;
        K1 = hi; K2 = m2 > lo ? m2 : lo;
      }
      if (partB == 0) rowres[browB] = K1;
    }
    __syncthreads();

    // ---- phase C: winner-entry owner recomputes its internal 2nd (exact) ----
#pragma unroll
    for (int mt = 0; mt < 4; mt++)
#pragma unroll
      for (int reg = 0; reg < 4; reg++) {
        int row = mt * 16 + q * 4 + reg;
        unsigned int kk1 = rowres[row];  // LDS broadcast across m-lanes
        int colw = 255 - (int)(kk1 & 255u);
        if ((colw >> 6) == wv && (colw & 15) == m) {
          int nt1 = (colw >> 4) & 3;
          unsigned int k2i = 0u;
#pragma unroll
          for (int nt = 0; nt < 4; nt++) {
            if (nt == nt1) continue;
            float v = acc[mt][nt][reg] + bias[nt];
            unsigned int col = (unsigned)(wv * 64 + nt * 16 + m);
            unsigned int key = (f2ord(v) & 0xFFFFFF00u) | (255u - col);
            k2i = k2i > key ? k2i : key;
          }
          rowres2[row] = k2i;
        }
      }
    __syncthreads();

    // ---- final: leader per row emits idx + near-tie flag ----
    if (partB == 0) {
      unsigned int k2f = rowres2[browB];
      k2f = k2f > K2 ? k2f : K2;
      int colw = 255 - (int)(K1 & 255u);
      int b = r0 + browB;
      idxbuf[b * 16 + seg] = colw;
      float v1 = ord2f(K1 & 0xFFFFFF00u);
      float v2 = ord2f(k2f & 0xFFFFFF00u);
      if (v1 - v2 < MARGIN2) {
        int p = atomicAdd(cnt, 1);
        if (p < FIX_CAP) list[p] = (b << 4) | seg;
      }
    }
    // no extra barrier: >=2 barriers separate this seg's kbuf/rowres/rowres2
    // readers from the next seg's writers (round-1 proven schedule).
  }
}

// ---------------------------------------------------------------------------
// K1fix: exact fp32 recompute for flagged (b,seg) — unchanged proven numerics.
// ---------------------------------------------------------------------------
__global__ __launch_bounds__(256) void k1_fix(
    const float* __restrict__ x, const float* __restrict__ W1,
    const float* __restrict__ b1, const int* __restrict__ cnt,
    const int* __restrict__ list, int* __restrict__ idxbuf) {
  __shared__ float redv[4];
  __shared__ int   redi[4];
  const int t = threadIdx.x;
  const int lane = t & 63, wv = t >> 6;
  int n = cnt[0]; if (n > FIX_CAP) n = FIX_CAP;
  for (int e = blockIdx.x; e < n; e += gridDim.x) {
    int pk = list[e];
    int b = pk >> 4, seg = pk & 15;
    int c = seg * 256 + t;
    float a = b1[c];
    const float4* xr = (const float4*)(x + b * 128);
    const float4* wr = (const float4*)(W1 + (size_t)c * 128);
#pragma unroll 8
    for (int k4 = 0; k4 < 32; k4++) {
      float4 xv = xr[k4];
      float4 wv4 = wr[k4];
      a = fmaf(xv.x, wv4.x, a);
      a = fmaf(xv.y, wv4.y, a);
      a = fmaf(xv.z, wv4.z, a);
      a = fmaf(xv.w, wv4.w, a);
    }
    float v = a; int li = t;
#pragma unroll
    for (int msk = 1; msk < 64; msk <<= 1) {
      float u = __shfl_xor(v, msk, 64);
      int ju = __shfl_xor(li, msk, 64);
      if (u > v || (u == v && ju < li)) { v = u; li = ju; }
    }
    if (lane == 0) { redv[wv] = v; redi[wv] = li; }
    __syncthreads();
    if (t == 0) {
      float bv = redv[0]; int bi = redi[0];
#pragma unroll
      for (int w = 1; w < 4; w++) {
        if (redv[w] > bv || (redv[w] == bv && redi[w] < bi)) { bv = redv[w]; bi = redi[w]; }
      }
      idxbuf[b * 16 + seg] = bi;
    }
    __syncthreads();
  }
}

// ---------------------------------------------------------------------------
// K2: Mt[c,k] += sum_j W2[j,c]*W3[k,j] via bf16 MFMA.
// v3: split-K 8 -> 16 (grid 64x16): k2 was grid-limited to 2 waves/SIMD
// (512 blocks); 1024 blocks -> 4 waves/SIMD for latency hiding of the
// strided scalar W2 loads. Same per-chunk FLOP order; only atomic grouping
// changes (jitter ~1e-7, absmax is bf16-quantization-dominated).
// ---------------------------------------------------------------------------
__global__ __launch_bounds__(256) void k2_mfma(const float* __restrict__ W2,
                                               const unsigned short* __restrict__ W3b,
                                               float* __restrict__ Mt) {
  const int t = threadIdx.x;
  const int lane = t & 63, wv = t >> 6;
  const int c0 = (blockIdx.x * 4 + wv) * 16;
  const int jq = blockIdx.y;                  // 16 K-chunks of 256
  const int m = lane & 15, q = lane >> 4;
  f32x4 acc[8];
#pragma unroll
  for (int nt = 0; nt < 8; nt++) acc[nt] = (f32x4){0.f, 0.f, 0.f, 0.f};

  for (int it = 0; it < 8; it++) {
    const int j0 = jq * 256 + it * 32;
    union { bf16x8 v; unsigned short u[8]; } a;
    const float* ap = W2 + (size_t)(j0 + q * 8) * 4096 + c0 + m;
#pragma unroll
    for (int i = 0; i < 8; i++) a.u[i] = f2bf(ap[(size_t)i * 4096]);
#pragma unroll
    for (int nt = 0; nt < 8; nt++) {
      bf16x8 b = *(const bf16x8*)(W3b + (nt * 16 + m) * 4096 + j0 + q * 8);
      acc[nt] = __builtin_amdgcn_mfma_f32_16x16x32_bf16(a.v, b, acc[nt], 0, 0, 0);
    }
  }
#pragma unroll
  for (int nt = 0; nt < 8; nt++)
#pragma unroll
    for (int r = 0; r < 4; r++)
      atomicAdd(&Mt[(size_t)(c0 + q * 4 + r) * 128 + nt * 16 + m], acc[nt][r]);
}

// ---------------------------------------------------------------------------
// K3: out[b,k] = const[k] + sum_g Mt[g*256 + idx[b,g], k]  (unchanged)
// ---------------------------------------------------------------------------
__global__ __launch_bounds__(256) void k3_gather(const int* __restrict__ idxbuf,
                                                 const float* __restrict__ Mt,
                                                 const float* __restrict__ constv,
                                                 float* __restrict__ out) {
  const int t = threadIdx.x;
  const int w = t >> 6;
  const int lane = t & 63;
  const int b = blockIdx.x * 4 + w;
  float a0 = constv[lane];
  float a1 = constv[lane + 64];
  const int* ib = idxbuf + b * 16;
  int cg[16];
#pragma unroll
  for (int g = 0; g < 16; g++) cg[g] = g * 256 + ib[g];
#pragma unroll
  for (int g = 0; g < 16; g++) {
    const float* mrow = Mt + (size_t)cg[g] * 128;
    a0 += mrow[lane];
    a1 += mrow[lane + 64];
  }
  out[b * 128 + lane] = a0;
  out[b * 128 + lane + 64] = a1;
}

// ---------------------------------------------------------------------------
extern "C" void kernel_launch(void* const* d_in, const int* in_sizes, int n_in,
                              void* d_out, int out_size, void* d_ws, size_t ws_size,
                              hipStream_t stream) {
  const float* x  = (const float*)d_in[0];
  const float* W1 = (const float*)d_in[1];
  const float* b1 = (const float*)d_in[2];
  const float* W2 = (const float*)d_in[3];
  const float* b2 = (const float*)d_in[4];
  const float* W3 = (const float*)d_in[5];
  const float* b3 = (const float*)d_in[6];
  float* out = (float*)d_out;

  char* w = (char*)d_ws;
  int* idxbuf         = (int*)(w);                           // 2 MB
  unsigned short* W3b = (unsigned short*)(w + (2u << 20));   // 1 MB
  float* Mt           = (float*)(w + (3u << 20));            // 2 MB
  unsigned short* w1h = (unsigned short*)(w + (5u << 20));   // 1 MB
  unsigned short* w1l = (unsigned short*)(w + (6u << 20));   // 1 MB
  float* constv       = (float*)(w + (7u << 20));            // 512 B
  int* cnt            = (int*)(w + (7u << 20) + 1024);       // 4 B
  int* fixlist        = (int*)(w + (7u << 20) + 4096);       // 256 KB

  kprep<<<1152, 256, 0, stream>>>(Mt, cnt, W3, W3b, W1, w1h, w1l, b2, b3, constv);
  k1_mfma<<<dim3(512, 2), 256, 0, stream>>>(x, w1h, w1l, b1, idxbuf, cnt, fixlist);
  k1_fix<<<1024, 256, 0, stream>>>(x, W1, b1, cnt, fixlist, idxbuf);
  k2_mfma<<<dim3(64, 16), 256, 0, stream>>>(W2, W3b, Mt);
  k3_gather<<<8192, 256, 0, stream>>>(idxbuf, Mt, constv, out);
}

// Round 4
// 352.215 us; speedup vs baseline: 1.2181x; 1.1914x over previous
//
#include <hip/hip_runtime.h>
#include <cstdint>
#include <cstddef>

typedef __attribute__((ext_vector_type(8))) short bf16x8;
typedef __attribute__((ext_vector_type(4))) float f32x4;
typedef __attribute__((ext_vector_type(8))) unsigned short ushort8;

#define FIX_CAP 65536
// quantized-key flag margin: proven 1e-3 + 2*2.4e-4 key-truncation slack (round-1/3 verified)
#define MARGIN2 1.5e-3f

__device__ __forceinline__ unsigned short f2bf(float f) {
  union { float f; unsigned int u; } x; x.f = f;
  unsigned int r = (x.u + 0x7fffu + ((x.u >> 16) & 1u)) >> 16;  // RNE
  return (unsigned short)r;
}
__device__ __forceinline__ float bf2f(unsigned short h) {
  union { unsigned int u; float f; } x; x.u = ((unsigned int)h) << 16;
  return x.f;
}
// monotone float -> sortable u32 ordinal
__device__ __forceinline__ unsigned int f2ord(float v) {
  unsigned int s = __float_as_uint(v);
  return s ^ ((unsigned int)((int)s >> 31) | 0x80000000u);
}
__device__ __forceinline__ float ord2f(unsigned int o) {
  unsigned int s = (o & 0x80000000u) ? (o ^ 0x80000000u) : ~o;
  return __uint_as_float(s);
}

// ---------------------------------------------------------------------------
// kprep: fused {zero Mt + cnt, W3->bf16, W1->hi/lo bf16, const[k]=W3[k,:]·b2+b3[k]}
// ---------------------------------------------------------------------------
__global__ __launch_bounds__(256) void kprep(
    float* __restrict__ Mt, int* __restrict__ cnt,
    const float* __restrict__ W3, unsigned short* __restrict__ W3b,
    const float* __restrict__ W1, unsigned short* __restrict__ w1h,
    unsigned short* __restrict__ w1l,
    const float* __restrict__ b2, const float* __restrict__ b3,
    float* __restrict__ constv) {
  __shared__ float red[4];
  const int bid = blockIdx.x;
  const int t = threadIdx.x;
  if (bid < 512) {
    int e = bid * 256 + t;  // 2 MB of zeros
    ((float4*)Mt)[e] = (float4){0.f, 0.f, 0.f, 0.f};
    if (e == 0) cnt[0] = 0;
  } else if (bid < 768) {
    int e = ((bid - 512) * 256 + t) * 8;  // W3 -> bf16
    float4 f0 = *(const float4*)(W3 + e);
    float4 f1 = *(const float4*)(W3 + e + 4);
    ushort8 v;
    v[0] = f2bf(f0.x); v[1] = f2bf(f0.y); v[2] = f2bf(f0.z); v[3] = f2bf(f0.w);
    v[4] = f2bf(f1.x); v[5] = f2bf(f1.y); v[6] = f2bf(f1.z); v[7] = f2bf(f1.w);
    *(ushort8*)(W3b + e) = v;
  } else if (bid < 1024) {
    int e = ((bid - 768) * 256 + t) * 8;  // W1 -> hi/lo bf16
    float ff[8];
    *(float4*)&ff[0] = *(const float4*)(W1 + e);
    *(float4*)&ff[4] = *(const float4*)(W1 + e + 4);
    ushort8 h, l;
#pragma unroll
    for (int i = 0; i < 8; i++) {
      unsigned short hi = f2bf(ff[i]);
      h[i] = hi;
      l[i] = f2bf(ff[i] - bf2f(hi));
    }
    *(ushort8*)(w1h + e) = h;
    *(ushort8*)(w1l + e) = l;
  } else {
    int k = bid - 1024;  // const[k]
    float s = 0.f;
    for (int j = t; j < 4096; j += 256) s += W3[k * 4096 + j] * b2[j];
#pragma unroll
    for (int mk = 1; mk < 64; mk <<= 1) s += __shfl_xor(s, mk, 64);
    if ((t & 63) == 0) red[t >> 6] = s;
    __syncthreads();
    if (t == 0) constv[k] = red[0] + red[1] + red[2] + red[3] + b3[k];
  }
}

// ---------------------------------------------------------------------------
// K1 v4: 512-thread blocks, swapped MFMA operands (A=W1, B=x).
//   Grid 512 blocks x 64 rows, 8 waves each -> 4096 waves = 4 waves/SIMD,
//   ALL co-resident in a single pass (no seg/row split, no tail, no idxbuf
//   line sharing). LDS 38.9 KB (x hi/lo + 4KB wavebuf); VGPR budget <=128
//   via acc[2][4] (wave covers 32 seg-cols x 64 rows).
// Swapped layout: D[w1col][xrow], lane&15 = x-row -> each thread holds 16
//   seg-col values (2a x 4reg) per x-row-tile b. Per-seg argmax becomes:
//   local top2-of-8 per b (VALU) -> 2-step q-butterfly -> wavebuf pair ->
//   t<64 merges 8 wave pairs. No kbuf, no claim pass, 2 barriers/seg.
// Term order mfma(wh,xh), mfma(wl,xh), mfma(wh,xl) == round-1's
//   xh*wh + xh*wl + xl*wh accumulation -> bit-identical logits.
// Flag criterion: quantized-key gap < 1.5e-3 (proven superset, k1_fix exact).
// ---------------------------------------------------------------------------
__global__ __launch_bounds__(512, 4) void k1_mfma(
    const float* __restrict__ x, const unsigned short* __restrict__ w1h,
    const unsigned short* __restrict__ w1l, const float* __restrict__ b1,
    int* __restrict__ idxbuf, int* __restrict__ cnt, int* __restrict__ list) {
  __shared__ unsigned short xsh[64 * 136];  // stride 136 shorts (proven layout)
  __shared__ unsigned short xsl[64 * 136];
  __shared__ uint2 wavebuf[8 * 64];         // [wave][row] sorted key pair

  const int t = threadIdx.x;
  const int r0 = blockIdx.x * 64;

  // ---- stage x rows 64x128, hi/lo bf16 split (once per block) ----
#pragma unroll
  for (int it = 0; it < 2; it++) {
    int ch = it * 512 + t;          // 1024 chunks of 8 elems
    int row = ch >> 4, k8 = ch & 15;
    float ff[8];
    *(float4*)&ff[0] = *(const float4*)(x + (r0 + row) * 128 + k8 * 8);
    *(float4*)&ff[4] = *(const float4*)(x + (r0 + row) * 128 + k8 * 8 + 4);
    ushort8 h, l;
#pragma unroll
    for (int i = 0; i < 8; i++) {
      unsigned short hi = f2bf(ff[i]);
      h[i] = hi;
      l[i] = f2bf(ff[i] - bf2f(hi));
    }
    *(ushort8*)&xsh[row * 136 + k8 * 8] = h;
    *(ushort8*)&xsl[row * 136 + k8 * 8] = l;
  }
  __syncthreads();

  const int lane = t & 63, w = t >> 6;      // 8 waves
  const int m = lane & 15, q = lane >> 4;

  for (int seg = 0; seg < 16; ++seg) {
    const int cb = seg * 256 + w * 32;      // wave's first seg-col (a=0,q=0,r=0)

    f32x4 acc[2][4];
#pragma unroll
    for (int a = 0; a < 2; a++)
#pragma unroll
      for (int b = 0; b < 4; b++) acc[a][b] = (f32x4){0.f, 0.f, 0.f, 0.f};

#pragma unroll
    for (int ks = 0; ks < 4; ks++) {
      const int k0 = ks * 32;
      // A-frags: W1 rows cb+a*16+m, k = k0+q*8 (global, L2-resident)
      bf16x8 ah[2], al[2];
#pragma unroll
      for (int a = 0; a < 2; a++) {
        const size_t woff = (size_t)(cb + a * 16 + m) * 128 + k0 + q * 8;
        ah[a] = *(const bf16x8*)(w1h + woff);
        al[a] = *(const bf16x8*)(w1l + woff);
      }
      // B-frags: x rows b*16+m from LDS, two pairs to cap VGPRs
#pragma unroll
      for (int bp = 0; bp < 2; bp++) {
        bf16x8 bh[2], bl[2];
#pragma unroll
        for (int bb = 0; bb < 2; bb++) {
          const int roff = ((bp * 2 + bb) * 16 + m) * 136 + k0 + q * 8;
          bh[bb] = *(const bf16x8*)&xsh[roff];
          bl[bb] = *(const bf16x8*)&xsl[roff];
        }
#pragma unroll
        for (int a = 0; a < 2; a++)
#pragma unroll
          for (int bb = 0; bb < 2; bb++) {
            const int b = bp * 2 + bb;
            acc[a][b] = __builtin_amdgcn_mfma_f32_16x16x32_bf16(ah[a], bh[bb], acc[a][b], 0, 0, 0);
            acc[a][b] = __builtin_amdgcn_mfma_f32_16x16x32_bf16(al[a], bh[bb], acc[a][b], 0, 0, 0);
            acc[a][b] = __builtin_amdgcn_mfma_f32_16x16x32_bf16(ah[a], bl[bb], acc[a][b], 0, 0, 0);
          }
      }
    }

    // ---- epilogue: per-row top-2 keys, register-local ----
    float4 bias4[2];
#pragma unroll
    for (int a = 0; a < 2; a++)
      bias4[a] = *(const float4*)&b1[cb + a * 16 + q * 4];

#pragma unroll
    for (int b = 0; b < 4; b++) {
      unsigned int K1 = 0u, K2 = 0u;
#pragma unroll
      for (int a = 0; a < 2; a++)
#pragma unroll
        for (int r = 0; r < 4; r++) {
          float v = acc[a][b][r] + bias4[a][r];
          unsigned int col = (unsigned)(w * 32 + a * 16 + q * 4 + r);
          unsigned int key = (f2ord(v) & 0xFFFFFF00u) | (255u - col);
          unsigned int mx = K1 > key ? K1 : key;
          unsigned int mn = K1 > key ? key : K1;
          K1 = mx; K2 = K2 > mn ? K2 : mn;
        }
      // butterfly over q (lanes xor 16, 32): row top-2 over wave's 32 cols
#pragma unroll
      for (int msk = 16; msk <= 32; msk <<= 1) {
        unsigned int p1 = (unsigned int)__shfl_xor((int)K1, msk, 64);
        unsigned int p2 = (unsigned int)__shfl_xor((int)K2, msk, 64);
        unsigned int mx = K1 > p1 ? K1 : p1;
        unsigned int mn = K1 > p1 ? p1 : K1;
        unsigned int sel = K1 >= p1 ? K2 : p2;
        K1 = mx;
        K2 = sel > mn ? sel : mn;
      }
      if (lane < 16) {  // q == 0
        uint2 pr; pr.x = K1; pr.y = K2;
        wavebuf[w * 64 + b * 16 + m] = pr;
      }
    }
    __syncthreads();

    // ---- merge 8 wave pairs per row; emit idx + near-tie flag ----
    if (t < 64) {
      unsigned int K1 = 0u, K2 = 0u;
#pragma unroll
      for (int wp = 0; wp < 8; wp++) {
        uint2 pr = wavebuf[wp * 64 + t];
        unsigned int mx = K1 > pr.x ? K1 : pr.x;
        unsigned int mn = K1 > pr.x ? pr.x : K1;
        unsigned int sel = K1 >= pr.x ? K2 : pr.y;
        K1 = mx;
        K2 = sel > mn ? sel : mn;
      }
      int colw = 255 - (int)(K1 & 255u);
      int bgl = r0 + t;
      idxbuf[bgl * 16 + seg] = colw;
      float v1 = ord2f(K1 & 0xFFFFFF00u);
      float v2 = ord2f(K2 & 0xFFFFFF00u);
      if (v1 - v2 < MARGIN2) {
        int p = atomicAdd(cnt, 1);
        if (p < FIX_CAP) list[p] = (bgl << 4) | seg;
      }
    }
    __syncthreads();  // protect wavebuf before next seg's writes
  }
}

// ---------------------------------------------------------------------------
// K1fix: exact fp32 recompute for flagged (b,seg) — unchanged proven numerics.
// ---------------------------------------------------------------------------
__global__ __launch_bounds__(256) void k1_fix(
    const float* __restrict__ x, const float* __restrict__ W1,
    const float* __restrict__ b1, const int* __restrict__ cnt,
    const int* __restrict__ list, int* __restrict__ idxbuf) {
  __shared__ float redv[4];
  __shared__ int   redi[4];
  const int t = threadIdx.x;
  const int lane = t & 63, wv = t >> 6;
  int n = cnt[0]; if (n > FIX_CAP) n = FIX_CAP;
  for (int e = blockIdx.x; e < n; e += gridDim.x) {
    int pk = list[e];
    int b = pk >> 4, seg = pk & 15;
    int c = seg * 256 + t;
    float a = b1[c];
    const float4* xr = (const float4*)(x + b * 128);
    const float4* wr = (const float4*)(W1 + (size_t)c * 128);
#pragma unroll 8
    for (int k4 = 0; k4 < 32; k4++) {
      float4 xv = xr[k4];
      float4 wv4 = wr[k4];
      a = fmaf(xv.x, wv4.x, a);
      a = fmaf(xv.y, wv4.y, a);
      a = fmaf(xv.z, wv4.z, a);
      a = fmaf(xv.w, wv4.w, a);
    }
    float v = a; int li = t;
#pragma unroll
    for (int msk = 1; msk < 64; msk <<= 1) {
      float u = __shfl_xor(v, msk, 64);
      int ju = __shfl_xor(li, msk, 64);
      if (u > v || (u == v && ju < li)) { v = u; li = ju; }
    }
    if (lane == 0) { redv[wv] = v; redi[wv] = li; }
    __syncthreads();
    if (t == 0) {
      float bv = redv[0]; int bi = redi[0];
#pragma unroll
      for (int w = 1; w < 4; w++) {
        if (redv[w] > bv || (redv[w] == bv && redi[w] < bi)) { bv = redv[w]; bi = redi[w]; }
      }
      idxbuf[b * 16 + seg] = bi;
    }
    __syncthreads();
  }
}

// ---------------------------------------------------------------------------
// K2 v4: Mt[c,k] += sum_j W2[j,c]*W3[k,j], splitK=8 (proven grouping).
// W2 now staged through LDS TRANSPOSED ([c][j] bf16, stride 40 shorts) with
// coalesced float4 global reads -> a-frag is one ds_read_b128 instead of 8
// latency-serialized strided scalar loads. MFMA inputs bit-identical
// (same f2bf(W2[j][c]) values at same frag positions).
// Block: 256 thr, c-tile 64 (4 waves x 16), 16 j-iters of 32.
// ---------------------------------------------------------------------------
__global__ __launch_bounds__(256) void k2_mfma(const float* __restrict__ W2,
                                               const unsigned short* __restrict__ W3b,
                                               float* __restrict__ Mt) {
  __shared__ unsigned short ldsT[64 * 40];  // [c_local][j_local], 80B rows (16B-mult)
  const int t = threadIdx.x;
  const int lane = t & 63, wv = t >> 6;
  const int c0 = blockIdx.x * 64;           // 64 blocks -> 4096 c
  const int jq = blockIdx.y;                // 8 K-chunks of 512
  const int m = lane & 15, q = lane >> 4;
  f32x4 acc[8];
#pragma unroll
  for (int nt = 0; nt < 8; nt++) acc[nt] = (f32x4){0.f, 0.f, 0.f, 0.f};

  for (int it = 0; it < 16; it++) {
    const int j0 = jq * 512 + it * 32;
    // stage 32 j x 64 c, transposed, f32->bf16
#pragma unroll
    for (int i = 0; i < 2; i++) {
      int fid = i * 256 + t;                // 512 float4s
      int jl = fid >> 4, cq = fid & 15;
      float4 v = *(const float4*)&W2[(size_t)(j0 + jl) * 4096 + c0 + cq * 4];
      ldsT[(cq * 4 + 0) * 40 + jl] = f2bf(v.x);
      ldsT[(cq * 4 + 1) * 40 + jl] = f2bf(v.y);
      ldsT[(cq * 4 + 2) * 40 + jl] = f2bf(v.z);
      ldsT[(cq * 4 + 3) * 40 + jl] = f2bf(v.w);
    }
    __syncthreads();
    bf16x8 av = *(const bf16x8*)&ldsT[(wv * 16 + m) * 40 + q * 8];
#pragma unroll
    for (int nt = 0; nt < 8; nt++) {
      bf16x8 b = *(const bf16x8*)(W3b + (nt * 16 + m) * 4096 + j0 + q * 8);
      acc[nt] = __builtin_amdgcn_mfma_f32_16x16x32_bf16(av, b, acc[nt], 0, 0, 0);
    }
    __syncthreads();
  }
#pragma unroll
  for (int nt = 0; nt < 8; nt++)
#pragma unroll
    for (int r = 0; r < 4; r++)
      atomicAdd(&Mt[(size_t)(c0 + wv * 16 + q * 4 + r) * 128 + nt * 16 + m], acc[nt][r]);
}

// ---------------------------------------------------------------------------
// K3: out[b,k] = const[k] + sum_g Mt[g*256 + idx[b,g], k]  (unchanged)
// ---------------------------------------------------------------------------
__global__ __launch_bounds__(256) void k3_gather(const int* __restrict__ idxbuf,
                                                 const float* __restrict__ Mt,
                                                 const float* __restrict__ constv,
                                                 float* __restrict__ out) {
  const int t = threadIdx.x;
  const int w = t >> 6;
  const int lane = t & 63;
  const int b = blockIdx.x * 4 + w;
  float a0 = constv[lane];
  float a1 = constv[lane + 64];
  const int* ib = idxbuf + b * 16;
  int cg[16];
#pragma unroll
  for (int g = 0; g < 16; g++) cg[g] = g * 256 + ib[g];
#pragma unroll
  for (int g = 0; g < 16; g++) {
    const float* mrow = Mt + (size_t)cg[g] * 128;
    a0 += mrow[lane];
    a1 += mrow[lane + 64];
  }
  out[b * 128 + lane] = a0;
  out[b * 128 + lane + 64] = a1;
}

// ---------------------------------------------------------------------------
extern "C" void kernel_launch(void* const* d_in, const int* in_sizes, int n_in,
                              void* d_out, int out_size, void* d_ws, size_t ws_size,
                              hipStream_t stream) {
  const float* x  = (const float*)d_in[0];
  const float* W1 = (const float*)d_in[1];
  const float* b1 = (const float*)d_in[2];
  const float* W2 = (const float*)d_in[3];
  const float* b2 = (const float*)d_in[4];
  const float* W3 = (const float*)d_in[5];
  const float* b3 = (const float*)d_in[6];
  float* out = (float*)d_out;

  char* w = (char*)d_ws;
  int* idxbuf         = (int*)(w);                           // 2 MB
  unsigned short* W3b = (unsigned short*)(w + (2u << 20));   // 1 MB
  float* Mt           = (float*)(w + (3u << 20));            // 2 MB
  unsigned short* w1h = (unsigned short*)(w + (5u << 20));   // 1 MB
  unsigned short* w1l = (unsigned short*)(w + (6u << 20));   // 1 MB
  float* constv       = (float*)(w + (7u << 20));            // 512 B
  int* cnt            = (int*)(w + (7u << 20) + 1024);       // 4 B
  int* fixlist        = (int*)(w + (7u << 20) + 4096);       // 256 KB

  kprep<<<1152, 256, 0, stream>>>(Mt, cnt, W3, W3b, W1, w1h, w1l, b2, b3, constv);
  k1_mfma<<<512, 512, 0, stream>>>(x, w1h, w1l, b1, idxbuf, cnt, fixlist);
  k1_fix<<<1024, 256, 0, stream>>>(x, W1, b1, cnt, fixlist, idxbuf);
  k2_mfma<<<dim3(64, 8), 256, 0, stream>>>(W2, W3b, Mt);
  k3_gather<<<8192, 256, 0, stream>>>(idxbuf, Mt, constv, out);
}